// Round 1
// baseline (586.695 us; speedup 1.0000x reference)
//
#include <hip/hip_runtime.h>
#include <math.h>

// B=4,H=16,L=1024,D=64. gumbel_softmax(hard=True) forward is EXACTLY one-hot:
//   m*  = argmax_m( 0.125 * dot(elu(q_l), elu(k_m)) + gumbel[l,m] )
//   out = drop_mask[l,m*] * elu(v[m*,:])
// 2 kernels (fixup fused into score — the 4 m-splits of a row share a block):
//  1. prep: k -> elu -> bf16 hi/lo split into d_ws (16 MB)
//  2. score_fused: barrier-free, LDS-free MFMA main loop (A=k, B=q -> C row=m,
//     col=l). Per-lane single top-2 over its own l-column; 4-way m-split.
//     Then in-block: LDS merge of the 4 partials, fp64-exact argmax of the
//     top-2 candidates, gather v, write out. No global partials, no 3rd launch.

#define BH      64
#define SEQ     1024
#define DIM     64
#define NSPLIT  4
#define MR      (SEQ / NSPLIT)    // 256 m per wave
#define NTILES  (MR / 32)         // 8
#define NTHR    256

typedef short bf16x8 __attribute__((ext_vector_type(8)));
typedef float f32x16 __attribute__((ext_vector_type(16)));

__device__ __forceinline__ float eluf(float x) { return x > 0.0f ? x : expm1f(x); }

__device__ __forceinline__ unsigned f2bf_bits(float x) {
    unsigned u = __float_as_uint(x);
    return (u + 0x7fffu + ((u >> 16) & 1u)) >> 16;   // RNE
}

__device__ __forceinline__ void split_bf16(float x, short& h, short& l) {
    unsigned hb = f2bf_bits(x);
    float hf = __uint_as_float(hb << 16);
    h = (short)hb;
    l = (short)f2bf_bits(x - hf);   // x - hf exact in fp32
}

// strict-> update keeps earliest (smallest m) on exact tie given ascending scan
__device__ __forceinline__ void top2_update(float v, int m,
                                            float& b1, int& i1,
                                            float& b2, int& i2) {
    bool gt1 = v > b1;
    bool gt2 = v > b2;
    float nb2 = gt1 ? b1 : (gt2 ? v : b2);
    int   ni2 = gt1 ? i1 : (gt2 ? m : i2);
    b1 = gt1 ? v : b1;
    i1 = gt1 ? m : i1;
    b2 = nb2; i2 = ni2;
}

// ---------------- kernel 1: k -> elu -> bf16 hi/lo ----------------
__global__ __launch_bounds__(NTHR)
void prep_k_kernel(const float4* __restrict__ k4,
                   short4* __restrict__ khi, short4* __restrict__ klo) {
    int f = blockIdx.x * NTHR + threadIdx.x;       // 1,048,576 float4s
    float4 val = k4[f];
    short4 hv, lv;
    split_bf16(eluf(val.x), hv.x, lv.x);
    split_bf16(eluf(val.y), hv.y, lv.y);
    split_bf16(eluf(val.z), hv.z, lv.z);
    split_bf16(eluf(val.w), hv.w, lv.w);
    khi[f] = hv;
    klo[f] = lv;
}

// ---------------- kernel 2: fused score + top-2 + fixup + out ----------------
// wave = (bh, l-tile of 32, m-split of 256). 2048 blocks x 4 waves; the 4
// waves of a block are the 4 m-splits of the SAME 32 rows -> merge in LDS.
// XCD swizzle: xcd = blockIdx&7 -> bh in [xcd*8, xcd*8+8): 2MB k-slice per L2.
__global__ __launch_bounds__(NTHR, 3)
void score_fused_kernel(const float* __restrict__ q,
                        const short* __restrict__ khi,
                        const short* __restrict__ klo,
                        const float* __restrict__ gum,
                        const float* __restrict__ k,
                        const float* __restrict__ v,
                        const float* __restrict__ drop,
                        float* __restrict__ out) {
    __shared__ int4  part[32][NSPLIT + 1];   // +1 pad: kill ds bank conflicts
    __shared__ int   msf[32];
    __shared__ float dropv[32];

    const int w    = threadIdx.x >> 6;
    const int lane = threadIdx.x & 63;
    const int lrow = lane & 31;
    const int half = lane >> 5;

    const int x     = blockIdx.x & 7;
    const int j     = blockIdx.x >> 3;     // 0..255
    const int bh    = x * 8 + (j & 7);
    const int ltile = j >> 3;              // 0..31
    const int l0    = ltile * 32;
    const int ms    = w * MR;

    const size_t row = (size_t)bh * SEQ + l0 + lrow;   // this lane's l-row

    // ---- q B-frags in registers (col=lane&31 -> l, d-octet = half) ----
    bf16x8 qh[4], ql[4];
    {
        const float4* q4 = (const float4*)q + row * 16;
        #pragma unroll
        for (int ks = 0; ks < 4; ++ks) {
            float4 a = q4[ks * 4 + half * 2];
            float4 b = q4[ks * 4 + half * 2 + 1];
            float e[8] = { eluf(a.x), eluf(a.y), eluf(a.z), eluf(a.w),
                           eluf(b.x), eluf(b.y), eluf(b.z), eluf(b.w) };
            #pragma unroll
            for (int t = 0; t < 8; ++t) {
                short h, l;
                split_bf16(e[t], h, l);
                qh[ks][t] = h;
                ql[ks][t] = l;
            }
        }
    }

    const short* kh_base = khi + ((size_t)(bh * SEQ + ms + lrow) * 64 + half * 8);
    const short* kl_base = klo + ((size_t)(bh * SEQ + ms + lrow) * 64 + half * 8);
    const float* gp      = gum + (row << 10) + ms + half * 4;

    float b1 = -INFINITY, b2 = -INFINITY;
    int   i1 = 0, i2 = 0;

    bf16x8 ah[2][4], al[2][4];
    float  g[2][16];

    // preload tile 0
    #pragma unroll
    for (int ks = 0; ks < 4; ++ks) {
        ah[0][ks] = *(const bf16x8*)(kh_base + ks * 16);
        al[0][ks] = *(const bf16x8*)(kl_base + ks * 16);
    }
    #pragma unroll
    for (int qd = 0; qd < 4; ++qd) {
        float4 t4 = *(const float4*)(gp + qd * 8);
        g[0][qd * 4 + 0] = t4.x; g[0][qd * 4 + 1] = t4.y;
        g[0][qd * 4 + 2] = t4.z; g[0][qd * 4 + 3] = t4.w;
    }

    #pragma unroll
    for (int t = 0; t < NTILES; ++t) {
        const int cur = t & 1, nxt = cur ^ 1;
        if (t < NTILES - 1) {
            #pragma unroll
            for (int ks = 0; ks < 4; ++ks) {
                ah[nxt][ks] = *(const bf16x8*)(kh_base + (t + 1) * 2048 + ks * 16);
                al[nxt][ks] = *(const bf16x8*)(kl_base + (t + 1) * 2048 + ks * 16);
            }
            #pragma unroll
            for (int qd = 0; qd < 4; ++qd) {
                float4 t4 = *(const float4*)(gp + (t + 1) * 32 + qd * 8);
                g[nxt][qd * 4 + 0] = t4.x; g[nxt][qd * 4 + 1] = t4.y;
                g[nxt][qd * 4 + 2] = t4.z; g[nxt][qd * 4 + 3] = t4.w;
            }
        }

        f32x16 acc = (f32x16)0.0f;
        #pragma unroll
        for (int ks = 0; ks < 4; ++ks) {
            acc = __builtin_amdgcn_mfma_f32_32x32x16_bf16(ah[cur][ks], qh[ks], acc, 0, 0, 0);
            acc = __builtin_amdgcn_mfma_f32_32x32x16_bf16(ah[cur][ks], ql[ks], acc, 0, 0, 0);
            acc = __builtin_amdgcn_mfma_f32_32x32x16_bf16(al[cur][ks], qh[ks], acc, 0, 0, 0);
        }

        // C mapping: m = ms + t*32 + 4*half + (r&3) + 8*(r>>2), l = lane&31
        const int mb = ms + t * 32 + half * 4;
        #pragma unroll
        for (int r = 0; r < 16; ++r) {
            float lg = fmaf(acc[r], 0.125f, g[cur][r]);
            top2_update(lg, mb + (r & 3) + 8 * (r >> 2), b1, i1, b2, i2);
        }
    }

    // merge half-pair (lanes p, p+32 share the same l-column)
    {
        float ob1 = __shfl_xor(b1, 32);
        int   oi1 = __shfl_xor(i1, 32);
        float ob2 = __shfl_xor(b2, 32);
        int   oi2 = __shfl_xor(i2, 32);
        top2_update(ob1, oi1, b1, i1, b2, i2);
        top2_update(ob2, oi2, b1, i1, b2, i2);
    }
    if (half == 0) {
        part[lrow][w] = make_int4(__float_as_int(b1), i1,
                                  __float_as_int(b2), i2);
    }
    __syncthreads();

    // ---- in-block fixup: wave 0 only (32 rows x 2 cands) ----
    const int tid = threadIdx.x;
    if (tid < 64) {
        const int rloc = tid >> 1;
        const int cand = tid & 1;
        const size_t rrow = (size_t)bh * SEQ + l0 + rloc;

        float fb1 = -INFINITY, fb2 = -INFINITY;
        int   fi1 = 0, fi2 = 0;
        #pragma unroll
        for (int s = 0; s < NSPLIT; ++s) {
            int4 p = part[rloc][s];
            top2_update(__int_as_float(p.x), p.y, fb1, fi1, fb2, fi2);
            top2_update(__int_as_float(p.z), p.w, fb1, fi1, fb2, fi2);
        }
        const int m = cand ? fi2 : fi1;

        const float4* q4r = (const float4*)q + rrow * 16;
        const float4* k4r = (const float4*)k + ((size_t)bh * SEQ + m) * 16;
        double s = 0.0;
        #pragma unroll
        for (int i = 0; i < 16; ++i) {
            float4 a = q4r[i], b = k4r[i];
            s += (double)eluf(a.x) * (double)eluf(b.x);
            s += (double)eluf(a.y) * (double)eluf(b.y);
            s += (double)eluf(a.z) * (double)eluf(b.z);
            s += (double)eluf(a.w) * (double)eluf(b.w);
        }
        double L  = s * 0.125 + (double)gum[(rrow << 10) + m];
        double Lo = __shfl_xor(L, 1);
        int    mo = __shfl_xor(m, 1);
        const int mstar = (L > Lo || (L == Lo && m < mo)) ? m : mo;
        if (cand == 0) {
            msf[rloc]   = mstar;
            dropv[rloc] = drop[(rrow << 10) + mstar];
        }
    }
    __syncthreads();

    // ---- out: 32 rows x 16 float4 = 512; 256 threads x 2 ----
    const float4* v4 = (const float4*)v + (size_t)bh * SEQ * 16;
    float4* o4 = (float4*)out + ((size_t)bh * SEQ + l0) * 16;
    #pragma unroll
    for (int i = 0; i < 2; ++i) {
        int f  = tid + NTHR * i;   // 0..511 = 32 rows x 16 quads
        int rr = f >> 4, qd = f & 15;
        int   mm = msf[rr];
        float dm = dropv[rr];
        float4 vv = v4[mm * 16 + qd];
        float4 ov;
        ov.x = dm * eluf(vv.x); ov.y = dm * eluf(vv.y);
        ov.z = dm * eluf(vv.z); ov.w = dm * eluf(vv.w);
        o4[rr * 16 + qd] = ov;
    }
}

extern "C" void kernel_launch(void* const* d_in, const int* in_sizes, int n_in,
                              void* d_out, int out_size, void* d_ws, size_t ws_size,
                              hipStream_t stream) {
    const float* q    = (const float*)d_in[0];
    const float* k    = (const float*)d_in[1];
    const float* v    = (const float*)d_in[2];
    const float* gum  = (const float*)d_in[3];
    const float* drop = (const float*)d_in[4];
    float* out = (float*)d_out;

    // ws: khi (8 MB) | klo (8 MB)  = 16 MB
    short* khi = (short*)d_ws;
    short* klo = khi + (size_t)BH * SEQ * DIM;

    prep_k_kernel<<<dim3((BH * SEQ * DIM / 4) / NTHR), dim3(NTHR), 0, stream>>>(
        (const float4*)k, (short4*)khi, (short4*)klo);
    score_fused_kernel<<<dim3(BH * (SEQ / 32) * NSPLIT / 4), dim3(NTHR), 0, stream>>>(
        q, khi, klo, gum, k, v, drop, out);
}

// Round 3
// 573.654 us; speedup vs baseline: 1.0227x; 1.0227x over previous
//
#include <hip/hip_runtime.h>
#include <math.h>

// B=4,H=16,L=1024,D=64. gumbel_softmax(hard=True) forward is EXACTLY one-hot:
//   m*  = argmax_m( 0.125 * dot(elu(q_l), elu(k_m)) + gumbel[l,m] )
//   out = drop_mask[l,m*] * elu(v[m*,:])
// 3 kernels:
//  1. prep: k -> 0.125*elu(k) -> bf16 (hi only) into d_ws (8 MB)
//  2. score: barrier-free, LDS-free MFMA (A=k_bf16, B=q split hi/lo).
//     gumbel rides in as the MFMA C-initializer (scale pre-folded into k).
//     Per-lane top-2 over its own (split,half) 128-m subset -> pool of 16/row.
//  3. fixup: pool merge; fp64 re-score ONLY candidates within DELTA of the
//     approx max (rare); gather v, write out.
// Register-lean: ~126 VGPR -> 4 blocks/CU (was 3 with AGPR shuffling).

#define BH      64
#define SEQ     1024
#define DIM     64
#define NSPLIT  4
#define MR      (SEQ / NSPLIT)    // 256 m per wave
#define NTILES  (MR / 32)         // 8
#define NTHR    256
#define NPOOL   8                 // int4 per row = top2 x (4 splits x 2 halves)
#define DELTA   0.05f             // fp64-rescore window (~70 sigma of bf16-k err)
#define FIXROWS 16

typedef short bf16x8 __attribute__((ext_vector_type(8)));
typedef float f32x16 __attribute__((ext_vector_type(16)));

__device__ __forceinline__ float eluf(float x) { return x > 0.0f ? x : expm1f(x); }

__device__ __forceinline__ unsigned f2bf_bits(float x) {
    unsigned u = __float_as_uint(x);
    return (u + 0x7fffu + ((u >> 16) & 1u)) >> 16;   // RNE
}

__device__ __forceinline__ void split_bf16(float x, short& h, short& l) {
    unsigned hb = f2bf_bits(x);
    float hf = __uint_as_float(hb << 16);
    h = (short)hb;
    l = (short)f2bf_bits(x - hf);   // x - hf exact in fp32
}

// strict-> update keeps earliest (smallest m) on exact tie given ascending scan
__device__ __forceinline__ void top2_update(float v, int m,
                                            float& b1, int& i1,
                                            float& b2, int& i2) {
    bool gt1 = v > b1;
    bool gt2 = v > b2;
    float nb2 = gt1 ? b1 : (gt2 ? v : b2);
    int   ni2 = gt1 ? i1 : (gt2 ? m : i2);
    b1 = gt1 ? v : b1;
    i1 = gt1 ? m : i1;
    b2 = nb2; i2 = ni2;
}

// ---------------- kernel 1: k -> 0.125*elu -> bf16 hi ----------------
__global__ __launch_bounds__(NTHR)
void prep_k_kernel(const float4* __restrict__ k4, short4* __restrict__ khi) {
    int f = blockIdx.x * NTHR + threadIdx.x;       // 1,048,576 float4s
    float4 val = k4[f];
    short4 hv;
    hv.x = (short)f2bf_bits(0.125f * eluf(val.x));
    hv.y = (short)f2bf_bits(0.125f * eluf(val.y));
    hv.z = (short)f2bf_bits(0.125f * eluf(val.z));
    hv.w = (short)f2bf_bits(0.125f * eluf(val.w));
    khi[f] = hv;
}

// ---------------- kernel 2: barrier-free score + per-subset top-2 ----------------
// wave = (bh, l-tile of 32, m-split of 256). 2048 blocks x 4 waves.
// XCD swizzle: xcd = blockIdx&7 -> bh in [xcd*8, xcd*8+8): 1MB k-slice per L2.
__global__ __launch_bounds__(NTHR, 4)
void score_kernel(const float* __restrict__ q,
                  const short* __restrict__ khi,
                  const float* __restrict__ gum,
                  int4* __restrict__ pool) {
    const int w    = threadIdx.x >> 6;
    const int lane = threadIdx.x & 63;
    const int lrow = lane & 31;
    const int half = lane >> 5;

    const int x     = blockIdx.x & 7;
    const int j     = blockIdx.x >> 3;     // 0..255
    const int bh    = x * 8 + (j & 7);
    const int ltile = j >> 3;              // 0..31
    const int l0    = ltile * 32;
    const int ms    = w * MR;

    const size_t row = (size_t)bh * SEQ + l0 + lrow;   // this lane's l-row

    // ---- q B-frags in registers (col=lane&31 -> l, d-octet = half) ----
    bf16x8 qh[4], ql[4];
    {
        const float4* q4 = (const float4*)q + row * 16;
        #pragma unroll
        for (int ks = 0; ks < 4; ++ks) {
            float4 a = q4[ks * 4 + half * 2];
            float4 b = q4[ks * 4 + half * 2 + 1];
            float e[8] = { eluf(a.x), eluf(a.y), eluf(a.z), eluf(a.w),
                           eluf(b.x), eluf(b.y), eluf(b.z), eluf(b.w) };
            #pragma unroll
            for (int t = 0; t < 8; ++t) {
                short h, l;
                split_bf16(e[t], h, l);
                qh[ks][t] = h;
                ql[ks][t] = l;
            }
        }
    }

    const short* kh_base = khi + ((size_t)(bh * SEQ + ms + lrow) * 64 + half * 8);
    const float* gp      = gum + (row << 10) + ms + half * 4;

    float b1 = -INFINITY, b2 = -INFINITY;
    int   i1 = 0, i2 = 0;

    bf16x8 ah[2][4];
    union GU { f32x16 v; float4 f4[4]; };
    GU g[2];

    // preload tile 0
    #pragma unroll
    for (int ks = 0; ks < 4; ++ks)
        ah[0][ks] = *(const bf16x8*)(kh_base + ks * 16);
    #pragma unroll
    for (int qd = 0; qd < 4; ++qd)
        g[0].f4[qd] = *(const float4*)(gp + qd * 8);

    #pragma unroll
    for (int t = 0; t < NTILES; ++t) {
        const int cur = t & 1, nxt = cur ^ 1;
        if (t < NTILES - 1) {
            #pragma unroll
            for (int ks = 0; ks < 4; ++ks)
                ah[nxt][ks] = *(const bf16x8*)(kh_base + (t + 1) * 2048 + ks * 16);
            #pragma unroll
            for (int qd = 0; qd < 4; ++qd)
                g[nxt].f4[qd] = *(const float4*)(gp + (t + 1) * 32 + qd * 8);
        }

        // logits = gumbel (C-init) + dot(q, 0.125*k)  [scale folded into khi]
        f32x16 acc = g[cur].v;
        #pragma unroll
        for (int ks = 0; ks < 4; ++ks) {
            acc = __builtin_amdgcn_mfma_f32_32x32x16_bf16(ah[cur][ks], qh[ks], acc, 0, 0, 0);
            acc = __builtin_amdgcn_mfma_f32_32x32x16_bf16(ah[cur][ks], ql[ks], acc, 0, 0, 0);
        }

        // C mapping: m = ms + t*32 + 4*half + (r&3) + 8*(r>>2), l = lane&31
        const int mb = ms + t * 32 + half * 4;
        #pragma unroll
        for (int r = 0; r < 16; ++r)
            top2_update(acc[r], mb + (r & 3) + 8 * (r >> 2), b1, i1, b2, i2);
    }

    // every lane owns a disjoint 128-m subset of its row: write its top-2
    pool[row * NPOOL + w + NSPLIT * half] =
        make_int4(__float_as_int(b1), i1, __float_as_int(b2), i2);
}

// ---------------- kernel 3: pool merge, rare fp64 fixup, emit out ----------------
// 4096 blocks x 256 thr; 16 rows/block (all same bh), 16 threads/row (cands).
__global__ __launch_bounds__(NTHR)
void fixup_out_kernel(const float* __restrict__ q,
                      const float* __restrict__ k,
                      const float* __restrict__ v,
                      const float* __restrict__ gum,
                      const float* __restrict__ drop,
                      const int4* __restrict__ pool,
                      float* __restrict__ out) {
    __shared__ int   msf[FIXROWS];
    __shared__ float dropv[FIXROWS];

    const int tid  = threadIdx.x;
    const int rloc = tid >> 4;          // 0..15
    const int cand = tid & 15;          // 0..15
    const size_t row = (size_t)blockIdx.x * FIXROWS + rloc;
    const int bh = (int)(row >> 10);

    int4 p = pool[row * NPOOL + (cand >> 1)];
    float val = (cand & 1) ? __int_as_float(p.z) : __int_as_float(p.x);
    int   m   = (cand & 1) ? p.w : p.y;

    // approx max over the 16-candidate pool (global approx max is in the pool)
    float mx = val;
    #pragma unroll
    for (int s = 1; s < 16; s <<= 1) mx = fmaxf(mx, __shfl_xor(mx, s));

    const bool active = (val >= mx - DELTA);
    unsigned long long bal = __ballot(active);
    const int gsh  = ((tid & 63) >> 4) << 4;     // 16-lane group within wave
    const int acnt = __popcll((bal >> gsh) & 0xFFFFull);

    // winner is exact unless >=2 candidates sit within DELTA of the max;
    // only then re-score the active ones in fp64.
    double Lv;
    if (!active) {
        Lv = -1.0e300;
    } else if (acnt <= 1) {
        Lv = 1.0;                                 // unique winner, no rescore
    } else {
        const float4* q4r = (const float4*)q + row * 16;
        const float4* k4r = (const float4*)k + ((size_t)bh * SEQ + m) * 16;
        double s = 0.0;
        #pragma unroll
        for (int i = 0; i < 16; ++i) {
            float4 a = q4r[i], b = k4r[i];
            s += (double)eluf(a.x) * (double)eluf(b.x);
            s += (double)eluf(a.y) * (double)eluf(b.y);
            s += (double)eluf(a.z) * (double)eluf(b.z);
            s += (double)eluf(a.w) * (double)eluf(b.w);
        }
        Lv = s * 0.125 + (double)gum[(row << 10) + m];
    }

    int mm = m;
    #pragma unroll
    for (int s = 1; s < 16; s <<= 1) {
        double Lo = __shfl_xor(Lv, s);
        int    mo = __shfl_xor(mm, s);
        if (Lo > Lv || (Lo == Lv && mo < mm)) { Lv = Lo; mm = mo; }
    }
    if (cand == 0) {
        msf[rloc]   = mm;
        dropv[rloc] = drop[(row << 10) + mm];
    }
    __syncthreads();

    // ---- out: 16 rows x 16 float4 = 256; one per thread ----
    const int bh0 = (int)(((size_t)blockIdx.x * FIXROWS) >> 10);
    const float4* v4 = (const float4*)v + (size_t)bh0 * SEQ * 16;
    float4* o4 = (float4*)out + (size_t)blockIdx.x * FIXROWS * 16;
    const int rr = tid >> 4, qd = tid & 15;
    const int   mmv = msf[rr];
    const float dm  = dropv[rr];
    float4 vv = v4[mmv * 16 + qd];
    float4 ov;
    ov.x = dm * eluf(vv.x); ov.y = dm * eluf(vv.y);
    ov.z = dm * eluf(vv.z); ov.w = dm * eluf(vv.w);
    o4[rr * 16 + qd] = ov;
}

extern "C" void kernel_launch(void* const* d_in, const int* in_sizes, int n_in,
                              void* d_out, int out_size, void* d_ws, size_t ws_size,
                              hipStream_t stream) {
    const float* q    = (const float*)d_in[0];
    const float* k    = (const float*)d_in[1];
    const float* v    = (const float*)d_in[2];
    const float* gum  = (const float*)d_in[3];
    const float* drop = (const float*)d_in[4];
    float* out = (float*)d_out;

    // ws: khi (8 MB) | pool (8 MB) = 16 MB
    short* khi  = (short*)d_ws;
    int4*  pool = (int4*)((char*)d_ws + (size_t)BH * SEQ * DIM * sizeof(short));

    prep_k_kernel<<<dim3((BH * SEQ * DIM / 4) / NTHR), dim3(NTHR), 0, stream>>>(
        (const float4*)k, (short4*)khi);
    score_kernel<<<dim3(BH * (SEQ / 32) * NSPLIT / 4), dim3(NTHR), 0, stream>>>(
        q, khi, gum, pool);
    fixup_out_kernel<<<dim3((BH * SEQ) / FIXROWS), dim3(NTHR), 0, stream>>>(
        q, k, v, gum, drop, pool, out);
}